// Round 16
// baseline (421.308 us; speedup 1.0000x reference)
//
#include <hip/hip_runtime.h>
#include <math.h>

#define QN 20000
#define PN 80000   // QN*4
#define CN 128
#define NVIEW 6

typedef __attribute__((ext_vector_type(8))) _Float16 h8;
typedef __attribute__((ext_vector_type(4))) _Float16 h4;
typedef __attribute__((ext_vector_type(4))) float f32x4;

__device__ __forceinline__ void gload16(const void* g, void* l) {
  __builtin_amdgcn_global_load_lds(
      (const __attribute__((address_space(1))) void*)g,
      (__attribute__((address_space(3))) void*)l, 16, 0, 0);
}

// ---------------- fused weight transpose: all 6 layers in one dispatch -------
__global__ __launch_bounds__(256) void wtrans_all(
    const float* __restrict__ w0, const float* __restrict__ w1,
    const float* __restrict__ w2, const float* __restrict__ w3,
    const float* __restrict__ w4, const float* __restrict__ w5,
    _Float16* __restrict__ base) {
  __shared__ float t[32][33];
  int b = blockIdx.x;
  const float* W; _Float16* T; int K, N, Kp, nbx, lb;
  if (b < 16)        { W = w0; T = base + 0;       K = 60;   N = 256;  Kp = 64;   nbx = 8;  lb = b; }
  else if (b < 48)   { W = w1; T = base + 32768;   K = 256;  N = 128;  Kp = 256;  nbx = 4;  lb = b - 16; }
  else if (b < 560)  { W = w2; T = base + 98304;   K = 512;  N = 1024; Kp = 512;  nbx = 32; lb = b - 48; }
  else if (b < 1584) { W = w3; T = base + 1146880; K = 1024; N = 1024; Kp = 1024; nbx = 32; lb = b - 560; }
  else if (b < 2608) { W = w4; T = base + 3244032; K = 1024; N = 1024; Kp = 1024; nbx = 32; lb = b - 1584; }
  else               { W = w5; T = base + 5341184; K = 1024; N = 128;  Kp = 1024; nbx = 4;  lb = b - 2608; }
  const int n0 = (lb % nbx) * 32, k0 = (lb / nbx) * 32;
  const int tx = threadIdx.x & 31, ty = threadIdx.x >> 5;  // ty 0..7
  #pragma unroll
  for (int j = 0; j < 4; ++j) {
    int k = k0 + ty + j * 8;
    t[ty + j * 8][tx] = (k < K) ? W[(size_t)k * N + n0 + tx] : 0.f;
  }
  __syncthreads();
  #pragma unroll
  for (int j = 0; j < 4; ++j) {
    int n = n0 + ty + j * 8;
    int k = k0 + tx;
    T[(size_t)n * Kp + k] = (_Float16)t[tx][ty + j * 8];
  }
}

// ---------------- feats f32 -> f16 (one concatenated plane) ------------------
__global__ __launch_bounds__(256) void fcvt_kernel(
    const float* __restrict__ s0, const float* __restrict__ s1,
    const float* __restrict__ s2, const float* __restrict__ s3,
    _Float16* __restrict__ d) {
  size_t i = (size_t)blockIdx.x * 256 + threadIdx.x;  // float4 index
  if (i >= 2872320) return;
  const float* s; size_t off;
  if (i < 2162688)      { s = s0; off = 0; }
  else if (i < 2703360) { s = s1; off = 2162688; }
  else if (i < 2838528) { s = s2; off = 2703360; }
  else                  { s = s3; off = 2838528; }
  f32x4 v = *(const f32x4*)(s + (i - off) * 4);
  h4 o;
  o[0] = (_Float16)v[0]; o[1] = (_Float16)v[1];
  o[2] = (_Float16)v[2]; o[3] = (_Float16)v[3];
  *(h4*)(d + i * 4) = o;
}

// ---------------- PE input features: sin/cos -> f16 [PN][64] -----------------
__global__ __launch_bounds__(256) void pe_in_kernel(const float* __restrict__ rp,
                                                    _Float16* __restrict__ P) {
  int idx = blockIdx.x * 256 + threadIdx.x;
  if (idx >= PN * 64) return;
  int p = idx >> 6, k = idx & 63;
  float val = 0.f;
  if (k < 60) {
    int q = p >> 2, z = p & 3;
    int d = k / 20, r = k - d * 20;
    int j = (r >= 10) ? (r - 10) : r;
    float pos = rp[((size_t)z * QN + q) * 3 + d];
    float ang = pos * ((float)(1 << j) * 3.14159265358979323846f);
    val = (r >= 10) ? cosf(ang) : sinf(ang);
  }
  P[idx] = (_Float16)val;
}

// ---------------- level-weight softmax: lw[p][4] = softmax(posE@wtw + wtb) ---
__global__ __launch_bounds__(256) void lw_kernel(const _Float16* __restrict__ posE,
                                                 const float* __restrict__ wtw,
                                                 const float* __restrict__ wtb,
                                                 float* __restrict__ lw) {
  __shared__ float swtT[512];  // transposed [4][128]
  __shared__ float sb[4];
  const int tid = threadIdx.x;
  for (int i = tid; i < 512; i += 256) swtT[(i & 3) * 128 + (i >> 2)] = wtw[i];
  if (tid < 4) sb[tid] = wtb[tid];
  __syncthreads();

  const int wave = tid >> 6, lane = tid & 63;
  const int grp = lane >> 4, s = lane & 15;
  const int p = blockIdx.x * 16 + wave * 4 + grp;
  const int c0 = s * 8;
  h8 pa = *(const h8*)(posE + (size_t)p * CN + c0);

  float lg[4];
  #pragma unroll
  for (int l = 0; l < 4; ++l) {
    const float* w = swtT + l * 128 + c0;
    float acc = 0.f;
    #pragma unroll
    for (int j = 0; j < 8; ++j) acc = fmaf((float)pa[j], w[j], acc);
    lg[l] = acc;
  }
  #pragma unroll
  for (int off = 8; off > 0; off >>= 1) {
    lg[0] += __shfl_xor(lg[0], off);
    lg[1] += __shfl_xor(lg[1], off);
    lg[2] += __shfl_xor(lg[2], off);
    lg[3] += __shfl_xor(lg[3], off);
  }
  lg[0] += sb[0]; lg[1] += sb[1]; lg[2] += sb[2]; lg[3] += sb[3];
  float mx = fmaxf(fmaxf(lg[0], lg[1]), fmaxf(lg[2], lg[3]));
  float e0 = __expf(lg[0] - mx), e1 = __expf(lg[1] - mx);
  float e2 = __expf(lg[2] - mx), e3 = __expf(lg[3] - mx);
  float esr = 1.f / (e0 + e1 + e2 + e3);
  if (s == 0) {
    f32x4 o = {e0 * esr, e1 * esr, e2 * esr, e3 * esr};
    *(f32x4*)(lw + (size_t)p * 4) = o;
  }
}

// ---------------- fp16 MFMA GEMM, A-in-LDS / B-direct-from-L2 ----------------
// r15 PMC: 128x128 LDS-staged GEMM is LDS-BW-bound (192KB LDS traffic/CU-step
// vs 307 MFMA cyc, MfmaUtil 25%). Fix: B fragments (weights, L2-resident)
// loaded straight global->VGPR (16B dwordx4, same bits as LDS path); only A
// staged in LDS (16KB total). B(t+1) prefetched into a second named register
// set before COMPUTE(t) -- latency hidden under MFMA, ordering handled by the
// compiler's vmcnt-at-barrier (proven r10 2-phase barrier structure intact).
// Requires nt = K/32 even (all layers comply). OUT=0: f32 C. OUT=1: f16 C.
template <bool RELU, int OUT>
__global__ __launch_bounds__(256, 3) void gemm_h(const _Float16* __restrict__ A,
                                                 const _Float16* __restrict__ B,
                                                 const float* __restrict__ bias,
                                                 float* __restrict__ Cf,
                                                 _Float16* __restrict__ Ch,
                                                 int M, int N, int K,
                                                 int nbn) {
  __shared__ _Float16 smA[2][128 * 32];  // 8 KB per buf, A only
  const int tid = threadIdx.x;
  const int wave = tid >> 6, lane = tid & 63;
  const int wr = wave >> 1, wc = wave & 1;
  const int g = lane >> 4, r16 = lane & 15;

  // bijective XCD swizzle (m204)
  const int nwg = gridDim.x;
  const int q8 = nwg >> 3, r8 = nwg & 7;
  const int xcd = blockIdx.x & 7, sub = blockIdx.x >> 3;
  const int wg = (xcd < r8 ? xcd * (q8 + 1) : r8 * (q8 + 1) + (xcd - r8) * q8) + sub;
  const int bn = (wg % nbn) * 128;
  const int bm = (wg / nbn) * 128;
  const int nt = K >> 5;  // K/32 tiles, even for all layers

  f32x4 acc[4][4];
  #pragma unroll
  for (int i = 0; i < 4; ++i)
    #pragma unroll
    for (int j = 0; j < 4; ++j) acc[i][j] = {0.f, 0.f, 0.f, 0.f};

  auto STAGE_A = [&](int buf, int t) {
    const int kof = t << 5;
    const int rsub = lane >> 2;                    // 0..15
    const int slot0 = lane & 3;
    #pragma unroll
    for (int i = 0; i < 2; ++i) {
      int group = wave * 2 + i;                    // 0..7
      int row = group * 16 + rsub;                 // 0..127
      int slot = slot0 ^ ((row >> 1) & 3);         // pre-swizzled source
      int gr = bm + row; if (gr >= M) gr = M - 1;
      gload16(A + (size_t)gr * K + kof + slot * 8,
              &smA[buf][group * 512]);             // linear LDS dest
    }
  };

  // B fragment: same bits the LDS path delivered -- 16B at B[row][kof + g*8]
  auto B_LOAD = [&](h8* b, int t) {
    const int kof = t << 5;
    #pragma unroll
    for (int ni = 0; ni < 4; ++ni) {
      int row = bn + wc * 64 + ni * 16 + r16;
      b[ni] = *(const h8*)(B + (size_t)row * K + kof + g * 8);
    }
  };

  auto COMPUTE = [&](int buf, const h8* b) {
    h8 a[4];
    #pragma unroll
    for (int mi = 0; mi < 4; ++mi) {
      int row = wr * 64 + mi * 16 + r16;
      int off = row * 32 + ((g ^ ((row >> 1) & 3)) * 8);  // swizzled read
      a[mi] = *(const h8*)&smA[buf][off];
    }
    #pragma unroll
    for (int mi = 0; mi < 4; ++mi)
      #pragma unroll
      for (int ni = 0; ni < 4; ++ni)
        acc[mi][ni] = __builtin_amdgcn_mfma_f32_16x16x32_f16(a[mi], b[ni], acc[mi][ni], 0, 0, 0);
  };

  h8 b0[4], b1[4];
  STAGE_A(0, 0);
  B_LOAD(b0, 0);
  __syncthreads();                 // vmcnt(0)+lgkmcnt(0)+barrier

  for (int t = 0; t < nt; t += 2) {
    STAGE_A(1, t + 1);             // prefetch next tile (issue only)
    B_LOAD(b1, t + 1);
    COMPUTE(0, b0);                // 16 MFMA overlap the loads
    __syncthreads();
    if (t + 2 < nt) {
      STAGE_A(0, t + 2);
      B_LOAD(b0, t + 2);
    }
    COMPUTE(1, b1);
    __syncthreads();
  }

  // epilogue: D row = (lane>>4)*4 + r, col = lane&15 within each 16x16 frag
  #pragma unroll
  for (int mi = 0; mi < 4; ++mi) {
    int gr0 = bm + wr * 64 + mi * 16 + (lane >> 4) * 4;
    #pragma unroll
    for (int ni = 0; ni < 4; ++ni) {
      int gc = bn + wc * 64 + ni * 16 + r16;
      float bv = bias[gc];
      #pragma unroll
      for (int r = 0; r < 4; ++r) {
        int row = gr0 + r;
        if (row >= M) continue;
        float v = acc[mi][ni][r] + bv;
        if (RELU) v = fmaxf(v, 0.f);
        if (OUT == 0) Cf[(size_t)row * N + gc] = v;
        else          Ch[(size_t)row * N + gc] = (_Float16)v;
      }
    }
  }
}

// ---------------- 64-row-tile fp16 GEMM for occupancy-starved layers ---------
// (r14-proven for PE2/H4; unchanged)
template <bool RELU, int OUT>
__global__ __launch_bounds__(128, 3) void gemm_h64(const _Float16* __restrict__ A,
                                                   const _Float16* __restrict__ B,
                                                   const float* __restrict__ bias,
                                                   float* __restrict__ Cf,
                                                   _Float16* __restrict__ Ch,
                                                   int M, int N, int K,
                                                   int nbn) {
  __shared__ _Float16 smA[2][64 * 32];   // 4 KB per buf
  __shared__ _Float16 smB[2][128 * 32];  // 8 KB per buf
  const int tid = threadIdx.x;
  const int wave = tid >> 6, lane = tid & 63;
  const int wc = wave;                   // 2 waves across N
  const int g = lane >> 4, r16 = lane & 15;

  const int nwg = gridDim.x;
  const int q8 = nwg >> 3, r8 = nwg & 7;
  const int xcd = blockIdx.x & 7, sub = blockIdx.x >> 3;
  const int wg = (xcd < r8 ? xcd * (q8 + 1) : r8 * (q8 + 1) + (xcd - r8) * q8) + sub;
  const int bn = (wg % nbn) * 128;
  const int bm = (wg / nbn) * 64;
  const int nt = K >> 5;

  f32x4 acc[4][4];
  #pragma unroll
  for (int i = 0; i < 4; ++i)
    #pragma unroll
    for (int j = 0; j < 4; ++j) acc[i][j] = {0.f, 0.f, 0.f, 0.f};

  auto STAGE = [&](int buf, int t) {
    const int kof = t << 5;
    const int rsub = lane >> 2;
    const int slot0 = lane & 3;
    #pragma unroll
    for (int i = 0; i < 2; ++i) {
      int group = wave * 2 + i;            // 0..3
      int row = group * 16 + rsub;         // 0..63
      int slot = slot0 ^ ((row >> 1) & 3);
      int gr = bm + row; if (gr >= M) gr = M - 1;
      gload16(A + (size_t)gr * K + kof + slot * 8, &smA[buf][group * 512]);
    }
    #pragma unroll
    for (int i = 0; i < 4; ++i) {
      int group = wave * 4 + i;            // 0..7
      int row = group * 16 + rsub;         // 0..127
      int slot = slot0 ^ ((row >> 1) & 3);
      gload16(B + (size_t)(bn + row) * K + kof + slot * 8, &smB[buf][group * 512]);
    }
  };

  auto COMPUTE = [&](int buf) {
    h8 a[4], b[4];
    #pragma unroll
    for (int mi = 0; mi < 4; ++mi) {
      int row = mi * 16 + r16;             // 0..63
      int off = row * 32 + ((g ^ ((row >> 1) & 3)) * 8);
      a[mi] = *(const h8*)&smA[buf][off];
    }
    #pragma unroll
    for (int ni = 0; ni < 4; ++ni) {
      int row = wc * 64 + ni * 16 + r16;
      int off = row * 32 + ((g ^ ((row >> 1) & 3)) * 8);
      b[ni] = *(const h8*)&smB[buf][off];
    }
    #pragma unroll
    for (int mi = 0; mi < 4; ++mi)
      #pragma unroll
      for (int ni = 0; ni < 4; ++ni)
        acc[mi][ni] = __builtin_amdgcn_mfma_f32_16x16x32_f16(a[mi], b[ni], acc[mi][ni], 0, 0, 0);
  };

  STAGE(0, 0);
  __syncthreads();

  for (int t = 0; t < nt; ++t) {
    if (t + 1 < nt) STAGE((t + 1) & 1, t + 1);
    COMPUTE(t & 1);
    __syncthreads();
  }

  #pragma unroll
  for (int mi = 0; mi < 4; ++mi) {
    int gr0 = bm + mi * 16 + (lane >> 4) * 4;
    #pragma unroll
    for (int ni = 0; ni < 4; ++ni) {
      int gc = bn + wc * 64 + ni * 16 + r16;
      float bv = bias[gc];
      #pragma unroll
      for (int r = 0; r < 4; ++r) {
        int row = gr0 + r;
        if (row >= M) continue;
        float v = acc[mi][ni][r] + bv;
        if (RELU) v = fmaxf(v, 0.f);
        if (OUT == 0) Cf[(size_t)row * N + gc] = v;
        else          Ch[(size_t)row * N + gc] = (_Float16)v;
      }
    }
  }
}

// ---------------- fused projection + bilinear sample -------------------------
// 2 pts/wave + interior fast path + f16 feats + precomputed lw (r15-proven)
__global__ __launch_bounds__(256) void sample_kernel(
    const _Float16* __restrict__ fbase,
    const float* __restrict__ rp, const float* __restrict__ l2i,
    const float* __restrict__ lw,
    const _Float16* __restrict__ posE, _Float16* __restrict__ X0) {
  __shared__ float sl2i[96];
  const int tid = threadIdx.x;
  if (tid < 96) sl2i[tid] = l2i[tid];
  __syncthreads();

  const _Float16* FL[4] = {fbase, fbase + 8650752, fbase + 10813440,
                           fbase + 11354112};

  const int wave = tid >> 6, lane = tid & 63;
  const int half = lane >> 5, s = lane & 31;
  const int p = blockIdx.x * 8 + wave * 2 + half;
  const int q = p >> 2, z = p & 3;

  const float X  = rp[((size_t)z * QN + q) * 3 + 0] * 100.f - 50.f;
  const float Y  = rp[((size_t)z * QN + q) * 3 + 1] * 100.f - 50.f;
  const float Zc = rp[((size_t)z * QN + q) * 3 + 2] * 8.f - 4.f;

  const int c0 = s * 4;
  h4 pa = *(const h4*)(posE + (size_t)p * CN + c0);
  const float pe0 = (float)pa[0], pe1 = (float)pa[1];
  const float pe2 = (float)pa[2], pe3 = (float)pa[3];

  f32x4 lw4 = *(const f32x4*)(lw + (size_t)p * 4);   // broadcast load
  float swl[4] = {lw4[0], lw4[1], lw4[2], lw4[3]};

  float a0 = 0.f, a1 = 0.f, a2 = 0.f, a3 = 0.f;
  for (int n = 0; n < NVIEW; n++) {
    const float* Mx = sl2i + n * 16;
    float cam0 = Mx[0] * X + Mx[1] * Y + Mx[2]  * Zc + Mx[3];
    float cam1 = Mx[4] * X + Mx[5] * Y + Mx[6]  * Zc + Mx[7];
    float cam2 = Mx[8] * X + Mx[9] * Y + Mx[10] * Zc + Mx[11];
    float denom = fmaxf(cam2, 1e-5f);
    float u = cam0 / denom * (1.f / 704.f);
    float v = cam1 / denom * (1.f / 256.f);
    bool valid = (cam2 > 1e-5f) & (u > 0.f) & (u < 1.f) & (v > 0.f) & (v < 1.f);
    if (!valid) continue;
    float px3 = u * 22.f - 0.5f, py3 = v * 8.f - 0.5f;
    bool interior = (px3 >= 0.f) & (py3 >= 0.f) & (px3 < 21.f) & (py3 < 7.f);
    if (interior) {
      #pragma unroll
      for (int l = 0; l < 4; l++) {
        const int Hl = 64 >> l, Wl = 176 >> l;
        float pxl = u * (float)Wl - 0.5f;
        float pyl = v * (float)Hl - 0.5f;
        float fx = floorf(pxl), fy = floorf(pyl);
        int x0 = (int)fx, y0 = (int)fy;
        float wx = pxl - fx, wy = pyl - fy;
        float w1r = wy * swl[l], w0r = swl[l] - w1r;
        float w01 = w0r * wx, w00 = w0r - w01;
        float w11 = w1r * wx, w10 = w1r - w11;
        const _Float16* cp = FL[l]
            + ((size_t)n * (Hl * Wl) + (size_t)(y0 * Wl + x0)) * CN + c0;
        h4 v00 = *(const h4*)(cp);
        h4 v01 = *(const h4*)(cp + CN);
        h4 v10 = *(const h4*)(cp + Wl * CN);
        h4 v11 = *(const h4*)(cp + Wl * CN + CN);
        a0 = fmaf(w00, (float)v00[0], fmaf(w01, (float)v01[0], fmaf(w10, (float)v10[0], fmaf(w11, (float)v11[0], a0))));
        a1 = fmaf(w00, (float)v00[1], fmaf(w01, (float)v01[1], fmaf(w10, (float)v10[1], fmaf(w11, (float)v11[1], a1))));
        a2 = fmaf(w00, (float)v00[2], fmaf(w01, (float)v01[2], fmaf(w10, (float)v10[2], fmaf(w11, (float)v11[2], a2))));
        a3 = fmaf(w00, (float)v00[3], fmaf(w01, (float)v01[3], fmaf(w10, (float)v10[3], fmaf(w11, (float)v11[3], a3))));
      }
    } else {
      #pragma unroll
      for (int l = 0; l < 4; l++) {
        const int Hl = 64 >> l, Wl = 176 >> l;
        float pxl = u * (float)Wl - 0.5f;
        float pyl = v * (float)Hl - 0.5f;
        float fx = floorf(pxl), fy = floorf(pyl);
        int x0 = (int)fx, y0 = (int)fy;
        float wx = pxl - fx, wy = pyl - fy;
        float w1r = wy * swl[l], w0r = swl[l] - w1r;
        const float wxs[2] = {1.f - wx, wx};
        const float wrs[2] = {w0r, w1r};
        const _Float16* fb = FL[l] + (size_t)n * (Hl * Wl) * CN;
        #pragma unroll
        for (int cy = 0; cy < 2; cy++) {
          #pragma unroll
          for (int cx = 0; cx < 2; cx++) {
            int xi = x0 + cx, yi = y0 + cy;
            bool inb = ((unsigned)xi < (unsigned)Wl) & ((unsigned)yi < (unsigned)Hl);
            int off = inb ? (yi * Wl + xi) * CN : 0;
            float wgt = inb ? (wrs[cy] * wxs[cx]) : 0.f;
            h4 vv = *(const h4*)(fb + off + c0);
            a0 = fmaf(wgt, (float)vv[0], a0);
            a1 = fmaf(wgt, (float)vv[1], a1);
            a2 = fmaf(wgt, (float)vv[2], a2);
            a3 = fmaf(wgt, (float)vv[3], a3);
          }
        }
      }
    }
  }
  h4 o;
  o[0] = (_Float16)(a0 + pe0);
  o[1] = (_Float16)(a1 + pe1);
  o[2] = (_Float16)(a2 + pe2);
  o[3] = (_Float16)(a3 + pe3);
  *(h4*)&X0[(size_t)p * CN + c0] = o;  // row q, col z*128+c0
}

extern "C" void kernel_launch(void* const* d_in, const int* in_sizes, int n_in,
                              void* d_out, int out_size, void* d_ws, size_t ws_size,
                              hipStream_t stream) {
  const float* feat0 = (const float*)d_in[0];
  const float* feat1 = (const float*)d_in[1];
  const float* feat2 = (const float*)d_in[2];
  const float* feat3 = (const float*)d_in[3];
  const float* rp    = (const float*)d_in[4];
  const float* l2i   = (const float*)d_in[5];
  const float* pe_w1 = (const float*)d_in[6];
  const float* pe_b1 = (const float*)d_in[7];
  const float* pe_w2 = (const float*)d_in[8];
  const float* pe_b2 = (const float*)d_in[9];
  const float* wt_w  = (const float*)d_in[10];
  const float* wt_b  = (const float*)d_in[11];
  const float* hm_w1 = (const float*)d_in[12];
  const float* hm_b1 = (const float*)d_in[13];
  const float* hm_w2 = (const float*)d_in[14];
  const float* hm_b2 = (const float*)d_in[15];
  const float* hm_w3 = (const float*)d_in[16];
  const float* hm_b3 = (const float*)d_in[17];
  const float* hm_w4 = (const float*)d_in[18];
  const float* hm_b4 = (const float*)d_in[19];
  float* out = (float*)d_out;

  char* ws = (char*)d_ws;
  typedef _Float16 h16;
  // weights: transposed f16 [N][Kp] (offsets in halves match wtrans_all)
  h16* wPE1 = (h16*)(ws + 0);         // 256x64
  h16* wPE2 = (h16*)(ws + 65536);     // 128x256
  h16* wH1  = (h16*)(ws + 196608);    // 1024x512
  h16* wH2  = (h16*)(ws + 2293760);   // 1024x1024
  h16* wH3  = (h16*)(ws + 6488064);   // 1024x1024
  h16* wH4  = (h16*)(ws + 10682368);  // 128x1024

  // activations (liveness-aliased)
  h16*   posE = (h16*)(ws + 11534336);   // [80000][128] f16
  float* lwga = (float*)(ws + 33000000); // [80000][4] f32 level weights
  h16*   hpe  = (h16*)(ws + 53000192);   // [80000][256] f16
  h16*   pein = (h16*)(ws + 94000128);   // [80000][64] f16
  h16*   X0   = (h16*)(ws + 53000192);   // [20000][512] f16 (hpe dead)
  h16*   H1   = (h16*)(ws + 94000128);   // [20000][1024] f16 (pein dead)
  h16*   H2   = (h16*)(ws + 11534336);   // (posE dead after sample)
  h16*   H3   = (h16*)(ws + 94000128);   // (H1 dead)
  h16*   f16b = (h16*)(ws + 136000000);  // feats f16, 22.98 MB

  // 0. weight transposes (one dispatch) + feats f32->f16
  wtrans_all<<<2736, 256, 0, stream>>>(pe_w1, pe_w2, hm_w1, hm_w2, hm_w3, hm_w4,
                                       (h16*)ws);
  fcvt_kernel<<<(2872320 + 255) / 256, 256, 0, stream>>>(feat0, feat1, feat2,
                                                         feat3, f16b);

  // 1. PE features (f16, K padded 60->64)
  pe_in_kernel<<<(PN * 64 + 255) / 256, 256, 0, stream>>>(rp, pein);

  // 2. PE MLP: 64 -> 256 (relu) -> 128 (f16 posE); PE2 on 64-row tiles
  gemm_h<true, 1><<<2 * 625, 256, 0, stream>>>(pein, wPE1, pe_b1, nullptr, hpe, PN, 256, 64, 2);
  gemm_h64<false, 1><<<1250, 128, 0, stream>>>(hpe, wPE2, pe_b2, nullptr, posE, PN, 128, 256, 1);

  // 2b. level-weight softmax
  lw_kernel<<<PN / 16, 256, 0, stream>>>(posE, wt_w, wt_b, lwga);

  // 3. fused projection + sampling -> X0 f16
  sample_kernel<<<PN / 8, 256, 0, stream>>>(f16b, rp, l2i, lwga, posE, X0);

  // 4. head MLP: 512 -> 1024 -> 1024 -> 1024 -> 128 (H4 on 64-row tiles)
  gemm_h<true, 1><<<8 * 157, 256, 0, stream>>>(X0, wH1, hm_b1, nullptr, H1, QN, 1024, 512, 8);
  gemm_h<true, 1><<<8 * 157, 256, 0, stream>>>(H1, wH2, hm_b2, nullptr, H2, QN, 1024, 1024, 8);
  gemm_h<true, 1><<<8 * 157, 256, 0, stream>>>(H2, wH3, hm_b3, nullptr, H3, QN, 1024, 1024, 8);
  gemm_h64<false, 0><<<313, 128, 0, stream>>>(H3, wH4, hm_b4, out, nullptr, QN, 128, 1024, 1);
}

// Round 17
// 318.187 us; speedup vs baseline: 1.3241x; 1.3241x over previous
//
#include <hip/hip_runtime.h>
#include <math.h>

#define QN 20000
#define PN 80000   // QN*4
#define CN 128
#define NVIEW 6

typedef __attribute__((ext_vector_type(8))) _Float16 h8;
typedef __attribute__((ext_vector_type(4))) _Float16 h4;
typedef __attribute__((ext_vector_type(4))) float f32x4;

__device__ __forceinline__ void gload16(const void* g, void* l) {
  __builtin_amdgcn_global_load_lds(
      (const __attribute__((address_space(1))) void*)g,
      (__attribute__((address_space(3))) void*)l, 16, 0, 0);
}

// ---------------- fused weight transpose: all 6 layers in one dispatch -------
// W[K][N] f32 -> T[N][Kp] f16 (K zero-padded to Kp). Per-block descriptor
// select; block counts: 16|32|512|1024|1024|128 = 2736.
__global__ __launch_bounds__(256) void wtrans_all(
    const float* __restrict__ w0, const float* __restrict__ w1,
    const float* __restrict__ w2, const float* __restrict__ w3,
    const float* __restrict__ w4, const float* __restrict__ w5,
    _Float16* __restrict__ base) {
  __shared__ float t[32][33];
  int b = blockIdx.x;
  const float* W; _Float16* T; int K, N, Kp, nbx, lb;
  if (b < 16)        { W = w0; T = base + 0;       K = 60;   N = 256;  Kp = 64;   nbx = 8;  lb = b; }
  else if (b < 48)   { W = w1; T = base + 32768;   K = 256;  N = 128;  Kp = 256;  nbx = 4;  lb = b - 16; }
  else if (b < 560)  { W = w2; T = base + 98304;   K = 512;  N = 1024; Kp = 512;  nbx = 32; lb = b - 48; }
  else if (b < 1584) { W = w3; T = base + 1146880; K = 1024; N = 1024; Kp = 1024; nbx = 32; lb = b - 560; }
  else if (b < 2608) { W = w4; T = base + 3244032; K = 1024; N = 1024; Kp = 1024; nbx = 32; lb = b - 1584; }
  else               { W = w5; T = base + 5341184; K = 1024; N = 128;  Kp = 1024; nbx = 4;  lb = b - 2608; }
  const int n0 = (lb % nbx) * 32, k0 = (lb / nbx) * 32;
  const int tx = threadIdx.x & 31, ty = threadIdx.x >> 5;  // ty 0..7
  #pragma unroll
  for (int j = 0; j < 4; ++j) {
    int k = k0 + ty + j * 8;
    t[ty + j * 8][tx] = (k < K) ? W[(size_t)k * N + n0 + tx] : 0.f;
  }
  __syncthreads();
  #pragma unroll
  for (int j = 0; j < 4; ++j) {
    int n = n0 + ty + j * 8;
    int k = k0 + tx;
    T[(size_t)n * Kp + k] = (_Float16)t[tx][ty + j * 8];
  }
}

// ---------------- PE input features: sin/cos -> f16 [PN][64] -----------------
__global__ __launch_bounds__(256) void pe_in_kernel(const float* __restrict__ rp,
                                                    _Float16* __restrict__ P) {
  int idx = blockIdx.x * 256 + threadIdx.x;
  if (idx >= PN * 64) return;
  int p = idx >> 6, k = idx & 63;
  float val = 0.f;
  if (k < 60) {
    int q = p >> 2, z = p & 3;
    int d = k / 20, r = k - d * 20;
    int j = (r >= 10) ? (r - 10) : r;
    float pos = rp[((size_t)z * QN + q) * 3 + d];
    float ang = pos * ((float)(1 << j) * 3.14159265358979323846f);
    val = (r >= 10) ? cosf(ang) : sinf(ang);
  }
  P[idx] = (_Float16)val;
}

// ---------------- fp16 MFMA GEMM: C = A[MxK] @ B^T[NxK] (+bias) --------------
// ROUND-10 PROVEN CONFIG -- local optimum confirmed by three failed probes:
// r9 counted-vmcnt (neutral), r11 128x256 tile (-2x, occupancy), r16
// B-direct-from-L2 (-1.6x, TA/L1 serialization on strided 16B fragments).
// 128x128 tile, BK=32, 2x2 waves, 4 blocks/CU, 2-phase pipeline with one
// __syncthreads per tile, XCD bijective swizzle (m204), slot ^= (row>>1)&3
// LDS involution. OUT=0: f32 C. OUT=1: f16 C.
template <bool RELU, int OUT>
__global__ __launch_bounds__(256, 4) void gemm_h(const _Float16* __restrict__ A,
                                                 const _Float16* __restrict__ B,
                                                 const float* __restrict__ bias,
                                                 float* __restrict__ Cf,
                                                 _Float16* __restrict__ Ch,
                                                 int M, int N, int K,
                                                 int nbn) {
  __shared__ _Float16 sm[2][2][4096];  // [buf][A,B][128 rows * 32 k]
  const int tid = threadIdx.x;
  const int wave = tid >> 6, lane = tid & 63;
  const int wr = wave >> 1, wc = wave & 1;
  const int g = lane >> 4, r16 = lane & 15;

  // bijective XCD swizzle (m204)
  const int nwg = gridDim.x;
  const int q8 = nwg >> 3, r8 = nwg & 7;
  const int xcd = blockIdx.x & 7, sub = blockIdx.x >> 3;
  const int wg = (xcd < r8 ? xcd * (q8 + 1) : r8 * (q8 + 1) + (xcd - r8) * q8) + sub;
  const int bn = (wg % nbn) * 128;
  const int bm = (wg / nbn) * 128;
  const int nt = K >> 5;  // K/32 tiles

  f32x4 acc[4][4];
  #pragma unroll
  for (int i = 0; i < 4; ++i)
    #pragma unroll
    for (int j = 0; j < 4; ++j) acc[i][j] = {0.f, 0.f, 0.f, 0.f};

  auto STAGE = [&](int buf, int t) {
    const int kof = t << 5;
    const int rsub = lane >> 2;                    // 0..15
    const int slot0 = lane & 3;
    #pragma unroll
    for (int pl = 0; pl < 2; ++pl) {
      const _Float16* P = (pl == 0) ? A : B;
      const int rbase = (pl == 0) ? bm : bn;
      #pragma unroll
      for (int i = 0; i < 2; ++i) {
        int group = wave * 2 + i;                  // 0..7
        int row = group * 16 + rsub;               // 0..127
        int slot = slot0 ^ ((row >> 1) & 3);       // pre-swizzled source
        int gr = rbase + row;
        if (pl == 0 && gr >= M) gr = M - 1;
        gload16(P + (size_t)gr * K + kof + slot * 8,
                &sm[buf][pl][group * 512]);        // linear LDS dest
      }
    }
  };

  auto COMPUTE = [&](int buf) {
    h8 a[4], b[4];
    #pragma unroll
    for (int mi = 0; mi < 4; ++mi) {
      int row = wr * 64 + mi * 16 + r16;
      int off = row * 32 + ((g ^ ((row >> 1) & 3)) * 8);  // swizzled read
      a[mi] = *(const h8*)&sm[buf][0][off];
    }
    #pragma unroll
    for (int ni = 0; ni < 4; ++ni) {
      int row = wc * 64 + ni * 16 + r16;
      int off = row * 32 + ((g ^ ((row >> 1) & 3)) * 8);
      b[ni] = *(const h8*)&sm[buf][1][off];
    }
    #pragma unroll
    for (int mi = 0; mi < 4; ++mi)
      #pragma unroll
      for (int ni = 0; ni < 4; ++ni)
        acc[mi][ni] = __builtin_amdgcn_mfma_f32_16x16x32_f16(a[mi], b[ni], acc[mi][ni], 0, 0, 0);
  };

  STAGE(0, 0);
  __syncthreads();                 // vmcnt(0)+lgkmcnt(0)+barrier

  for (int t = 0; t < nt; ++t) {
    if (t + 1 < nt) STAGE((t + 1) & 1, t + 1);  // prefetch next (issue only)
    COMPUTE(t & 1);                             // 16 MFMA overlap the loads
    __syncthreads();               // drain prefetch + WAR fence, once per tile
  }

  #pragma unroll
  for (int mi = 0; mi < 4; ++mi) {
    int gr0 = bm + wr * 64 + mi * 16 + (lane >> 4) * 4;
    #pragma unroll
    for (int ni = 0; ni < 4; ++ni) {
      int gc = bn + wc * 64 + ni * 16 + r16;
      float bv = bias[gc];
      #pragma unroll
      for (int r = 0; r < 4; ++r) {
        int row = gr0 + r;
        if (row >= M) continue;
        float v = acc[mi][ni][r] + bv;
        if (RELU) v = fmaxf(v, 0.f);
        if (OUT == 0) Cf[(size_t)row * N + gc] = v;
        else          Ch[(size_t)row * N + gc] = (_Float16)v;
      }
    }
  }
}

// ---------------- fused softmax + projection + bilinear sample --------------
// 2 points per wave + interior fast path (best-measured r13 config: 317.9us).
// posE f16; feats f32 (f16-feats + fcvt was net-neutral, r14).
__global__ __launch_bounds__(256) void sample_kernel(
    const float* __restrict__ f0, const float* __restrict__ f1,
    const float* __restrict__ f2, const float* __restrict__ f3,
    const float* __restrict__ rp, const float* __restrict__ l2i,
    const float* __restrict__ wtw, const float* __restrict__ wtb,
    const _Float16* __restrict__ posE, _Float16* __restrict__ X0) {
  __shared__ float sl2i[96];
  __shared__ float swtT[512];  // transposed [4][128]
  __shared__ float sb[4];
  const int tid = threadIdx.x;
  if (tid < 96) sl2i[tid] = l2i[tid];
  for (int i = tid; i < 512; i += 256) swtT[(i & 3) * 128 + (i >> 2)] = wtw[i];
  if (tid < 4) sb[tid] = wtb[tid];
  __syncthreads();

  const int wave = tid >> 6, lane = tid & 63;
  const int half = lane >> 5, s = lane & 31;
  const int p = blockIdx.x * 8 + wave * 2 + half;
  const int q = p >> 2, z = p & 3;

  const float X  = rp[((size_t)z * QN + q) * 3 + 0] * 100.f - 50.f;
  const float Y  = rp[((size_t)z * QN + q) * 3 + 1] * 100.f - 50.f;
  const float Zc = rp[((size_t)z * QN + q) * 3 + 2] * 8.f - 4.f;

  const int c0 = s * 4;
  h4 pa = *(const h4*)(posE + (size_t)p * CN + c0);
  const float pe0 = (float)pa[0], pe1 = (float)pa[1];
  const float pe2 = (float)pa[2], pe3 = (float)pa[3];

  float l0 = pe0 * swtT[0 * 128 + c0] + pe1 * swtT[0 * 128 + c0 + 1]
           + pe2 * swtT[0 * 128 + c0 + 2] + pe3 * swtT[0 * 128 + c0 + 3];
  float l1 = pe0 * swtT[1 * 128 + c0] + pe1 * swtT[1 * 128 + c0 + 1]
           + pe2 * swtT[1 * 128 + c0 + 2] + pe3 * swtT[1 * 128 + c0 + 3];
  float l2 = pe0 * swtT[2 * 128 + c0] + pe1 * swtT[2 * 128 + c0 + 1]
           + pe2 * swtT[2 * 128 + c0 + 2] + pe3 * swtT[2 * 128 + c0 + 3];
  float l3 = pe0 * swtT[3 * 128 + c0] + pe1 * swtT[3 * 128 + c0 + 1]
           + pe2 * swtT[3 * 128 + c0 + 2] + pe3 * swtT[3 * 128 + c0 + 3];
  #pragma unroll
  for (int off = 16; off > 0; off >>= 1) {  // within-half butterfly
    l0 += __shfl_xor(l0, off);
    l1 += __shfl_xor(l1, off);
    l2 += __shfl_xor(l2, off);
    l3 += __shfl_xor(l3, off);
  }
  l0 += sb[0]; l1 += sb[1]; l2 += sb[2]; l3 += sb[3];
  float mx = fmaxf(fmaxf(l0, l1), fmaxf(l2, l3));
  float ex0 = __expf(l0 - mx), ex1 = __expf(l1 - mx);
  float ex2 = __expf(l2 - mx), ex3 = __expf(l3 - mx);
  float esr = 1.f / (ex0 + ex1 + ex2 + ex3);
  float swl[4] = {ex0 * esr, ex1 * esr, ex2 * esr, ex3 * esr};

  const float* FT[4] = {f0, f1, f2, f3};

  float a0 = 0.f, a1 = 0.f, a2 = 0.f, a3 = 0.f;
  for (int n = 0; n < NVIEW; n++) {
    const float* Mx = sl2i + n * 16;
    float cam0 = Mx[0] * X + Mx[1] * Y + Mx[2]  * Zc + Mx[3];
    float cam1 = Mx[4] * X + Mx[5] * Y + Mx[6]  * Zc + Mx[7];
    float cam2 = Mx[8] * X + Mx[9] * Y + Mx[10] * Zc + Mx[11];
    float denom = fmaxf(cam2, 1e-5f);
    float u = cam0 / denom * (1.f / 704.f);
    float v = cam1 / denom * (1.f / 256.f);
    bool valid = (cam2 > 1e-5f) & (u > 0.f) & (u < 1.f) & (v > 0.f) & (v < 1.f);
    if (!valid) continue;
    // interior test on the coarsest level (22x8): implies all levels interior
    float px3 = u * 22.f - 0.5f, py3 = v * 8.f - 0.5f;
    bool interior = (px3 >= 0.f) & (py3 >= 0.f) & (px3 < 21.f) & (py3 < 7.f);
    if (interior) {
      #pragma unroll
      for (int l = 0; l < 4; l++) {
        const int Hl = 64 >> l, Wl = 176 >> l;
        float pxl = u * (float)Wl - 0.5f;
        float pyl = v * (float)Hl - 0.5f;
        float fx = floorf(pxl), fy = floorf(pyl);
        int x0 = (int)fx, y0 = (int)fy;
        float wx = pxl - fx, wy = pyl - fy;
        float w1r = wy * swl[l], w0r = swl[l] - w1r;   // row weights * level w
        float w01 = w0r * wx, w00 = w0r - w01;
        float w11 = w1r * wx, w10 = w1r - w11;
        const float* cp = FT[l]
            + ((size_t)n * (Hl * Wl) + (size_t)(y0 * Wl + x0)) * CN + c0;
        f32x4 v00 = *(const f32x4*)(cp);
        f32x4 v01 = *(const f32x4*)(cp + CN);
        f32x4 v10 = *(const f32x4*)(cp + Wl * CN);
        f32x4 v11 = *(const f32x4*)(cp + Wl * CN + CN);
        a0 = fmaf(w00, v00[0], fmaf(w01, v01[0], fmaf(w10, v10[0], fmaf(w11, v11[0], a0))));
        a1 = fmaf(w00, v00[1], fmaf(w01, v01[1], fmaf(w10, v10[1], fmaf(w11, v11[1], a1))));
        a2 = fmaf(w00, v00[2], fmaf(w01, v01[2], fmaf(w10, v10[2], fmaf(w11, v11[2], a2))));
        a3 = fmaf(w00, v00[3], fmaf(w01, v01[3], fmaf(w10, v10[3], fmaf(w11, v11[3], a3))));
      }
    } else {
      #pragma unroll
      for (int l = 0; l < 4; l++) {
        const int Hl = 64 >> l, Wl = 176 >> l;
        float pxl = u * (float)Wl - 0.5f;
        float pyl = v * (float)Hl - 0.5f;
        float fx = floorf(pxl), fy = floorf(pyl);
        int x0 = (int)fx, y0 = (int)fy;
        float wx = pxl - fx, wy = pyl - fy;
        float w1r = wy * swl[l], w0r = swl[l] - w1r;
        const float wxs[2] = {1.f - wx, wx};
        const float wrs[2] = {w0r, w1r};
        const float* fb = FT[l] + (size_t)n * (Hl * Wl * CN);
        #pragma unroll
        for (int cy = 0; cy < 2; cy++) {
          #pragma unroll
          for (int cx = 0; cx < 2; cx++) {
            int xi = x0 + cx, yi = y0 + cy;
            bool inb = ((unsigned)xi < (unsigned)Wl) & ((unsigned)yi < (unsigned)Hl);
            int off = inb ? (yi * Wl + xi) * CN : 0;
            float wgt = inb ? (wrs[cy] * wxs[cx]) : 0.f;
            f32x4 vv = *(const f32x4*)(fb + off + c0);
            a0 = fmaf(wgt, vv[0], a0);
            a1 = fmaf(wgt, vv[1], a1);
            a2 = fmaf(wgt, vv[2], a2);
            a3 = fmaf(wgt, vv[3], a3);
          }
        }
      }
    }
  }
  h4 o;
  o[0] = (_Float16)(a0 + pe0);
  o[1] = (_Float16)(a1 + pe1);
  o[2] = (_Float16)(a2 + pe2);
  o[3] = (_Float16)(a3 + pe3);
  *(h4*)&X0[(size_t)p * CN + c0] = o;  // row q, col z*128+c0
}

extern "C" void kernel_launch(void* const* d_in, const int* in_sizes, int n_in,
                              void* d_out, int out_size, void* d_ws, size_t ws_size,
                              hipStream_t stream) {
  const float* feat0 = (const float*)d_in[0];
  const float* feat1 = (const float*)d_in[1];
  const float* feat2 = (const float*)d_in[2];
  const float* feat3 = (const float*)d_in[3];
  const float* rp    = (const float*)d_in[4];
  const float* l2i   = (const float*)d_in[5];
  const float* pe_w1 = (const float*)d_in[6];
  const float* pe_b1 = (const float*)d_in[7];
  const float* pe_w2 = (const float*)d_in[8];
  const float* pe_b2 = (const float*)d_in[9];
  const float* wt_w  = (const float*)d_in[10];
  const float* wt_b  = (const float*)d_in[11];
  const float* hm_w1 = (const float*)d_in[12];
  const float* hm_b1 = (const float*)d_in[13];
  const float* hm_w2 = (const float*)d_in[14];
  const float* hm_b2 = (const float*)d_in[15];
  const float* hm_w3 = (const float*)d_in[16];
  const float* hm_b3 = (const float*)d_in[17];
  const float* hm_w4 = (const float*)d_in[18];
  const float* hm_b4 = (const float*)d_in[19];
  float* out = (float*)d_out;

  char* ws = (char*)d_ws;
  typedef _Float16 h16;
  // weights: transposed f16 [N][Kp] (offsets in halves match wtrans_all)
  h16* wPE1 = (h16*)(ws + 0);         // 256x64
  h16* wPE2 = (h16*)(ws + 65536);     // 128x256
  h16* wH1  = (h16*)(ws + 196608);    // 1024x512
  h16* wH2  = (h16*)(ws + 2293760);   // 1024x1024
  h16* wH3  = (h16*)(ws + 6488064);   // 1024x1024
  h16* wH4  = (h16*)(ws + 10682368);  // 128x1024

  // activations (liveness-aliased)
  h16* posE = (h16*)(ws + 11534336);   // [80000][128] f16
  h16* hpe  = (h16*)(ws + 53000192);   // [80000][256] f16
  h16* pein = (h16*)(ws + 94000128);   // [80000][64] f16
  h16* X0   = (h16*)(ws + 53000192);   // [20000][512] f16 (hpe dead)
  h16* H1   = (h16*)(ws + 94000128);   // [20000][1024] f16 (pein dead)
  h16* H2   = (h16*)(ws + 11534336);   // (posE dead after sample)
  h16* H3   = (h16*)(ws + 94000128);   // (H1 dead)

  // 0. all weight transposes in one dispatch
  wtrans_all<<<2736, 256, 0, stream>>>(pe_w1, pe_w2, hm_w1, hm_w2, hm_w3, hm_w4,
                                       (h16*)ws);

  // 1. PE features (f16, K padded 60->64)
  pe_in_kernel<<<(PN * 64 + 255) / 256, 256, 0, stream>>>(rp, pein);

  // 2. PE MLP: 64 -> 256 (relu) -> 128 (f16 posE)
  gemm_h<true, 1><<<2 * 625, 256, 0, stream>>>(pein, wPE1, pe_b1, nullptr, hpe, PN, 256, 64, 2);
  gemm_h<false, 1><<<1 * 625, 256, 0, stream>>>(hpe, wPE2, pe_b2, nullptr, posE, PN, 128, 256, 1);

  // 3. fused softmax + projection + sampling -> X0 f16
  sample_kernel<<<PN / 8, 256, 0, stream>>>(feat0, feat1, feat2, feat3, rp, l2i,
                                            wt_w, wt_b, posE, X0);

  // 4. head MLP: 512 -> 1024 -> 1024 -> 1024 -> 128
  gemm_h<true, 1><<<8 * 157, 256, 0, stream>>>(X0, wH1, hm_b1, nullptr, H1, QN, 1024, 512, 8);
  gemm_h<true, 1><<<8 * 157, 256, 0, stream>>>(H1, wH2, hm_b2, nullptr, H2, QN, 1024, 1024, 8);
  gemm_h<true, 1><<<8 * 157, 256, 0, stream>>>(H2, wH3, hm_b3, nullptr, H3, QN, 1024, 1024, 8);
  gemm_h<false, 0><<<1 * 157, 256, 0, stream>>>(H3, wH4, hm_b4, out, nullptr, QN, 128, 1024, 1);
}

// Round 18
// 314.306 us; speedup vs baseline: 1.3404x; 1.0123x over previous
//
#include <hip/hip_runtime.h>
#include <math.h>

#define QN 20000
#define PN 80000   // QN*4
#define CN 128
#define NVIEW 6

typedef __attribute__((ext_vector_type(8))) _Float16 h8;
typedef __attribute__((ext_vector_type(4))) _Float16 h4;
typedef __attribute__((ext_vector_type(4))) float f32x4;

__device__ __forceinline__ void gload16(const void* g, void* l) {
  __builtin_amdgcn_global_load_lds(
      (const __attribute__((address_space(1))) void*)g,
      (__attribute__((address_space(3))) void*)l, 16, 0, 0);
}

// ---------------- prep mega-dispatch: wtrans(6 layers) + fcvt + pe_in --------
// blocks [0,2736): weight transpose W[K][N] f32 -> T[N][Kp] f16
// blocks [2736,13956): feats f32 -> f16 concatenated plane (11220 blocks)
// blocks [13956,33956): PE sin/cos features -> f16 [PN][64] (20000 blocks)
// All independent (read inputs, write ws) -> one dispatch = true overlap vs
// 3 serialized kernels (~19us -> ~10us).
__global__ __launch_bounds__(256) void prep_all(
    const float* __restrict__ w0, const float* __restrict__ w1,
    const float* __restrict__ w2, const float* __restrict__ w3,
    const float* __restrict__ w4, const float* __restrict__ w5,
    _Float16* __restrict__ wbase,
    const float* __restrict__ s0, const float* __restrict__ s1,
    const float* __restrict__ s2, const float* __restrict__ s3,
    _Float16* __restrict__ fdst,
    const float* __restrict__ rp, _Float16* __restrict__ pedst) {
  int b = blockIdx.x;
  if (b < 2736) {  // ---- weight transpose ----
    __shared__ float t[32][33];
    const float* W; _Float16* T; int K, N, Kp, nbx, lb;
    if (b < 16)        { W = w0; T = wbase + 0;       K = 60;   N = 256;  Kp = 64;   nbx = 8;  lb = b; }
    else if (b < 48)   { W = w1; T = wbase + 32768;   K = 256;  N = 128;  Kp = 256;  nbx = 4;  lb = b - 16; }
    else if (b < 560)  { W = w2; T = wbase + 98304;   K = 512;  N = 1024; Kp = 512;  nbx = 32; lb = b - 48; }
    else if (b < 1584) { W = w3; T = wbase + 1146880; K = 1024; N = 1024; Kp = 1024; nbx = 32; lb = b - 560; }
    else if (b < 2608) { W = w4; T = wbase + 3244032; K = 1024; N = 1024; Kp = 1024; nbx = 32; lb = b - 1584; }
    else               { W = w5; T = wbase + 5341184; K = 1024; N = 128;  Kp = 1024; nbx = 4;  lb = b - 2608; }
    const int n0 = (lb % nbx) * 32, k0 = (lb / nbx) * 32;
    const int tx = threadIdx.x & 31, ty = threadIdx.x >> 5;
    #pragma unroll
    for (int j = 0; j < 4; ++j) {
      int k = k0 + ty + j * 8;
      t[ty + j * 8][tx] = (k < K) ? W[(size_t)k * N + n0 + tx] : 0.f;
    }
    __syncthreads();
    #pragma unroll
    for (int j = 0; j < 4; ++j) {
      int n = n0 + ty + j * 8;
      int k = k0 + tx;
      T[(size_t)n * Kp + k] = (_Float16)t[tx][ty + j * 8];
    }
  } else if (b < 13956) {  // ---- feats f32 -> f16 ----
    size_t i = (size_t)(b - 2736) * 256 + threadIdx.x;  // float4 index
    const float* s; size_t off;
    if (i < 2162688)      { s = s0; off = 0; }
    else if (i < 2703360) { s = s1; off = 2162688; }
    else if (i < 2838528) { s = s2; off = 2703360; }
    else                  { s = s3; off = 2838528; }
    f32x4 v = *(const f32x4*)(s + (i - off) * 4);
    h4 o;
    o[0] = (_Float16)v[0]; o[1] = (_Float16)v[1];
    o[2] = (_Float16)v[2]; o[3] = (_Float16)v[3];
    *(h4*)(fdst + i * 4) = o;
  } else {  // ---- PE features ----
    int idx = (b - 13956) * 256 + threadIdx.x;
    int p = idx >> 6, k = idx & 63;
    float val = 0.f;
    if (k < 60) {
      int q = p >> 2, z = p & 3;
      int d = k / 20, r = k - d * 20;
      int j = (r >= 10) ? (r - 10) : r;
      float pos = rp[((size_t)z * QN + q) * 3 + d];
      float ang = pos * ((float)(1 << j) * 3.14159265358979323846f);
      val = (r >= 10) ? cosf(ang) : sinf(ang);
    }
    pedst[idx] = (_Float16)val;
  }
}

// ---------------- level-weight softmax: lw[p][4] = softmax(posE@wtw + wtb) ---
// (r15-proven: removed sample's preamble; 4 pts/wave, h8 loads)
__global__ __launch_bounds__(256) void lw_kernel(const _Float16* __restrict__ posE,
                                                 const float* __restrict__ wtw,
                                                 const float* __restrict__ wtb,
                                                 float* __restrict__ lw) {
  __shared__ float swtT[512];  // transposed [4][128]
  __shared__ float sb[4];
  const int tid = threadIdx.x;
  for (int i = tid; i < 512; i += 256) swtT[(i & 3) * 128 + (i >> 2)] = wtw[i];
  if (tid < 4) sb[tid] = wtb[tid];
  __syncthreads();

  const int wave = tid >> 6, lane = tid & 63;
  const int grp = lane >> 4, s = lane & 15;
  const int p = blockIdx.x * 16 + wave * 4 + grp;
  const int c0 = s * 8;
  h8 pa = *(const h8*)(posE + (size_t)p * CN + c0);

  float lg[4];
  #pragma unroll
  for (int l = 0; l < 4; ++l) {
    const float* w = swtT + l * 128 + c0;
    float acc = 0.f;
    #pragma unroll
    for (int j = 0; j < 8; ++j) acc = fmaf((float)pa[j], w[j], acc);
    lg[l] = acc;
  }
  #pragma unroll
  for (int off = 8; off > 0; off >>= 1) {
    lg[0] += __shfl_xor(lg[0], off);
    lg[1] += __shfl_xor(lg[1], off);
    lg[2] += __shfl_xor(lg[2], off);
    lg[3] += __shfl_xor(lg[3], off);
  }
  lg[0] += sb[0]; lg[1] += sb[1]; lg[2] += sb[2]; lg[3] += sb[3];
  float mx = fmaxf(fmaxf(lg[0], lg[1]), fmaxf(lg[2], lg[3]));
  float e0 = __expf(lg[0] - mx), e1 = __expf(lg[1] - mx);
  float e2 = __expf(lg[2] - mx), e3 = __expf(lg[3] - mx);
  float esr = 1.f / (e0 + e1 + e2 + e3);
  if (s == 0) {
    f32x4 o = {e0 * esr, e1 * esr, e2 * esr, e3 * esr};
    *(f32x4*)(lw + (size_t)p * 4) = o;
  }
}

// ---------------- fp16 MFMA GEMM: C = A[MxK] @ B^T[NxK] (+bias) --------------
// ROUND-10 PROVEN CONFIG -- local optimum (r9/r11/r16 probes all failed).
// 128x128, BK=32, 2x2 waves, 4 blocks/CU, 2-phase pipeline, one __syncthreads
// per tile, XCD bijective swizzle, slot^=(row>>1)&3 LDS involution.
template <bool RELU, int OUT>
__global__ __launch_bounds__(256, 4) void gemm_h(const _Float16* __restrict__ A,
                                                 const _Float16* __restrict__ B,
                                                 const float* __restrict__ bias,
                                                 float* __restrict__ Cf,
                                                 _Float16* __restrict__ Ch,
                                                 int M, int N, int K,
                                                 int nbn) {
  __shared__ _Float16 sm[2][2][4096];  // [buf][A,B][128 rows * 32 k]
  const int tid = threadIdx.x;
  const int wave = tid >> 6, lane = tid & 63;
  const int wr = wave >> 1, wc = wave & 1;
  const int g = lane >> 4, r16 = lane & 15;

  const int nwg = gridDim.x;
  const int q8 = nwg >> 3, r8 = nwg & 7;
  const int xcd = blockIdx.x & 7, sub = blockIdx.x >> 3;
  const int wg = (xcd < r8 ? xcd * (q8 + 1) : r8 * (q8 + 1) + (xcd - r8) * q8) + sub;
  const int bn = (wg % nbn) * 128;
  const int bm = (wg / nbn) * 128;
  const int nt = K >> 5;

  f32x4 acc[4][4];
  #pragma unroll
  for (int i = 0; i < 4; ++i)
    #pragma unroll
    for (int j = 0; j < 4; ++j) acc[i][j] = {0.f, 0.f, 0.f, 0.f};

  auto STAGE = [&](int buf, int t) {
    const int kof = t << 5;
    const int rsub = lane >> 2;
    const int slot0 = lane & 3;
    #pragma unroll
    for (int pl = 0; pl < 2; ++pl) {
      const _Float16* P = (pl == 0) ? A : B;
      const int rbase = (pl == 0) ? bm : bn;
      #pragma unroll
      for (int i = 0; i < 2; ++i) {
        int group = wave * 2 + i;
        int row = group * 16 + rsub;
        int slot = slot0 ^ ((row >> 1) & 3);
        int gr = rbase + row;
        if (pl == 0 && gr >= M) gr = M - 1;
        gload16(P + (size_t)gr * K + kof + slot * 8,
                &sm[buf][pl][group * 512]);
      }
    }
  };

  auto COMPUTE = [&](int buf) {
    h8 a[4], b[4];
    #pragma unroll
    for (int mi = 0; mi < 4; ++mi) {
      int row = wr * 64 + mi * 16 + r16;
      int off = row * 32 + ((g ^ ((row >> 1) & 3)) * 8);
      a[mi] = *(const h8*)&sm[buf][0][off];
    }
    #pragma unroll
    for (int ni = 0; ni < 4; ++ni) {
      int row = wc * 64 + ni * 16 + r16;
      int off = row * 32 + ((g ^ ((row >> 1) & 3)) * 8);
      b[ni] = *(const h8*)&sm[buf][1][off];
    }
    #pragma unroll
    for (int mi = 0; mi < 4; ++mi)
      #pragma unroll
      for (int ni = 0; ni < 4; ++ni)
        acc[mi][ni] = __builtin_amdgcn_mfma_f32_16x16x32_f16(a[mi], b[ni], acc[mi][ni], 0, 0, 0);
  };

  STAGE(0, 0);
  __syncthreads();

  for (int t = 0; t < nt; ++t) {
    if (t + 1 < nt) STAGE((t + 1) & 1, t + 1);
    COMPUTE(t & 1);
    __syncthreads();
  }

  #pragma unroll
  for (int mi = 0; mi < 4; ++mi) {
    int gr0 = bm + wr * 64 + mi * 16 + (lane >> 4) * 4;
    #pragma unroll
    for (int ni = 0; ni < 4; ++ni) {
      int gc = bn + wc * 64 + ni * 16 + r16;
      float bv = bias[gc];
      #pragma unroll
      for (int r = 0; r < 4; ++r) {
        int row = gr0 + r;
        if (row >= M) continue;
        float v = acc[mi][ni][r] + bv;
        if (RELU) v = fmaxf(v, 0.f);
        if (OUT == 0) Cf[(size_t)row * N + gc] = v;
        else          Ch[(size_t)row * N + gc] = (_Float16)v;
      }
    }
  }
}

// ---------------- fused projection + bilinear sample -------------------------
// 2 pts/wave + interior fast path (r13) + f16 feats (r14: FETCH 217->88MB)
// + precomputed lw (r15: preamble removed). All three individually verified.
__global__ __launch_bounds__(256) void sample_kernel(
    const _Float16* __restrict__ fbase,
    const float* __restrict__ rp, const float* __restrict__ l2i,
    const float* __restrict__ lw,
    const _Float16* __restrict__ posE, _Float16* __restrict__ X0) {
  __shared__ float sl2i[96];
  const int tid = threadIdx.x;
  if (tid < 96) sl2i[tid] = l2i[tid];
  __syncthreads();

  const _Float16* FL[4] = {fbase, fbase + 8650752, fbase + 10813440,
                           fbase + 11354112};

  const int wave = tid >> 6, lane = tid & 63;
  const int half = lane >> 5, s = lane & 31;
  const int p = blockIdx.x * 8 + wave * 2 + half;
  const int q = p >> 2, z = p & 3;

  const float X  = rp[((size_t)z * QN + q) * 3 + 0] * 100.f - 50.f;
  const float Y  = rp[((size_t)z * QN + q) * 3 + 1] * 100.f - 50.f;
  const float Zc = rp[((size_t)z * QN + q) * 3 + 2] * 8.f - 4.f;

  const int c0 = s * 4;
  h4 pa = *(const h4*)(posE + (size_t)p * CN + c0);
  const float pe0 = (float)pa[0], pe1 = (float)pa[1];
  const float pe2 = (float)pa[2], pe3 = (float)pa[3];

  f32x4 lw4 = *(const f32x4*)(lw + (size_t)p * 4);   // broadcast load
  float swl[4] = {lw4[0], lw4[1], lw4[2], lw4[3]};

  float a0 = 0.f, a1 = 0.f, a2 = 0.f, a3 = 0.f;
  for (int n = 0; n < NVIEW; n++) {
    const float* Mx = sl2i + n * 16;
    float cam0 = Mx[0] * X + Mx[1] * Y + Mx[2]  * Zc + Mx[3];
    float cam1 = Mx[4] * X + Mx[5] * Y + Mx[6]  * Zc + Mx[7];
    float cam2 = Mx[8] * X + Mx[9] * Y + Mx[10] * Zc + Mx[11];
    float denom = fmaxf(cam2, 1e-5f);
    float u = cam0 / denom * (1.f / 704.f);
    float v = cam1 / denom * (1.f / 256.f);
    bool valid = (cam2 > 1e-5f) & (u > 0.f) & (u < 1.f) & (v > 0.f) & (v < 1.f);
    if (!valid) continue;
    float px3 = u * 22.f - 0.5f, py3 = v * 8.f - 0.5f;
    bool interior = (px3 >= 0.f) & (py3 >= 0.f) & (px3 < 21.f) & (py3 < 7.f);
    if (interior) {
      #pragma unroll
      for (int l = 0; l < 4; l++) {
        const int Hl = 64 >> l, Wl = 176 >> l;
        float pxl = u * (float)Wl - 0.5f;
        float pyl = v * (float)Hl - 0.5f;
        float fx = floorf(pxl), fy = floorf(pyl);
        int x0 = (int)fx, y0 = (int)fy;
        float wx = pxl - fx, wy = pyl - fy;
        float w1r = wy * swl[l], w0r = swl[l] - w1r;
        float w01 = w0r * wx, w00 = w0r - w01;
        float w11 = w1r * wx, w10 = w1r - w11;
        const _Float16* cp = FL[l]
            + ((size_t)n * (Hl * Wl) + (size_t)(y0 * Wl + x0)) * CN + c0;
        h4 v00 = *(const h4*)(cp);
        h4 v01 = *(const h4*)(cp + CN);
        h4 v10 = *(const h4*)(cp + Wl * CN);
        h4 v11 = *(const h4*)(cp + Wl * CN + CN);
        a0 = fmaf(w00, (float)v00[0], fmaf(w01, (float)v01[0], fmaf(w10, (float)v10[0], fmaf(w11, (float)v11[0], a0))));
        a1 = fmaf(w00, (float)v00[1], fmaf(w01, (float)v01[1], fmaf(w10, (float)v10[1], fmaf(w11, (float)v11[1], a1))));
        a2 = fmaf(w00, (float)v00[2], fmaf(w01, (float)v01[2], fmaf(w10, (float)v10[2], fmaf(w11, (float)v11[2], a2))));
        a3 = fmaf(w00, (float)v00[3], fmaf(w01, (float)v01[3], fmaf(w10, (float)v10[3], fmaf(w11, (float)v11[3], a3))));
      }
    } else {
      #pragma unroll
      for (int l = 0; l < 4; l++) {
        const int Hl = 64 >> l, Wl = 176 >> l;
        float pxl = u * (float)Wl - 0.5f;
        float pyl = v * (float)Hl - 0.5f;
        float fx = floorf(pxl), fy = floorf(pyl);
        int x0 = (int)fx, y0 = (int)fy;
        float wx = pxl - fx, wy = pyl - fy;
        float w1r = wy * swl[l], w0r = swl[l] - w1r;
        const float wxs[2] = {1.f - wx, wx};
        const float wrs[2] = {w0r, w1r};
        const _Float16* fb = FL[l] + (size_t)n * (Hl * Wl) * CN;
        #pragma unroll
        for (int cy = 0; cy < 2; cy++) {
          #pragma unroll
          for (int cx = 0; cx < 2; cx++) {
            int xi = x0 + cx, yi = y0 + cy;
            bool inb = ((unsigned)xi < (unsigned)Wl) & ((unsigned)yi < (unsigned)Hl);
            int off = inb ? (yi * Wl + xi) * CN : 0;
            float wgt = inb ? (wrs[cy] * wxs[cx]) : 0.f;
            h4 vv = *(const h4*)(fb + off + c0);
            a0 = fmaf(wgt, (float)vv[0], a0);
            a1 = fmaf(wgt, (float)vv[1], a1);
            a2 = fmaf(wgt, (float)vv[2], a2);
            a3 = fmaf(wgt, (float)vv[3], a3);
          }
        }
      }
    }
  }
  h4 o;
  o[0] = (_Float16)(a0 + pe0);
  o[1] = (_Float16)(a1 + pe1);
  o[2] = (_Float16)(a2 + pe2);
  o[3] = (_Float16)(a3 + pe3);
  *(h4*)&X0[(size_t)p * CN + c0] = o;  // row q, col z*128+c0
}

extern "C" void kernel_launch(void* const* d_in, const int* in_sizes, int n_in,
                              void* d_out, int out_size, void* d_ws, size_t ws_size,
                              hipStream_t stream) {
  const float* feat0 = (const float*)d_in[0];
  const float* feat1 = (const float*)d_in[1];
  const float* feat2 = (const float*)d_in[2];
  const float* feat3 = (const float*)d_in[3];
  const float* rp    = (const float*)d_in[4];
  const float* l2i   = (const float*)d_in[5];
  const float* pe_w1 = (const float*)d_in[6];
  const float* pe_b1 = (const float*)d_in[7];
  const float* pe_w2 = (const float*)d_in[8];
  const float* pe_b2 = (const float*)d_in[9];
  const float* wt_w  = (const float*)d_in[10];
  const float* wt_b  = (const float*)d_in[11];
  const float* hm_w1 = (const float*)d_in[12];
  const float* hm_b1 = (const float*)d_in[13];
  const float* hm_w2 = (const float*)d_in[14];
  const float* hm_b2 = (const float*)d_in[15];
  const float* hm_w3 = (const float*)d_in[16];
  const float* hm_b3 = (const float*)d_in[17];
  const float* hm_w4 = (const float*)d_in[18];
  const float* hm_b4 = (const float*)d_in[19];
  float* out = (float*)d_out;

  char* ws = (char*)d_ws;
  typedef _Float16 h16;
  // weights: transposed f16 [N][Kp] (offsets in halves match prep_all)
  h16* wPE1 = (h16*)(ws + 0);         // 256x64
  h16* wPE2 = (h16*)(ws + 65536);     // 128x256
  h16* wH1  = (h16*)(ws + 196608);    // 1024x512
  h16* wH2  = (h16*)(ws + 2293760);   // 1024x1024
  h16* wH3  = (h16*)(ws + 6488064);   // 1024x1024
  h16* wH4  = (h16*)(ws + 10682368);  // 128x1024

  // activations (liveness-aliased)
  h16*   posE = (h16*)(ws + 11534336);   // [80000][128] f16
  float* lwga = (float*)(ws + 33000000); // [80000][4] f32 level weights
  h16*   hpe  = (h16*)(ws + 53000192);   // [80000][256] f16
  h16*   pein = (h16*)(ws + 94000128);   // [80000][64] f16
  h16*   X0   = (h16*)(ws + 53000192);   // [20000][512] f16 (hpe dead)
  h16*   H1   = (h16*)(ws + 94000128);   // [20000][1024] f16 (pein dead)
  h16*   H2   = (h16*)(ws + 11534336);   // (posE dead after sample)
  h16*   H3   = (h16*)(ws + 94000128);   // (H1 dead)
  h16*   f16b = (h16*)(ws + 136000000);  // feats f16, 22.98 MB, live thru sample

  // 0. single prep dispatch: weight transpose + feats f32->f16 + PE features
  prep_all<<<33956, 256, 0, stream>>>(pe_w1, pe_w2, hm_w1, hm_w2, hm_w3, hm_w4,
                                      (h16*)ws, feat0, feat1, feat2, feat3,
                                      f16b, rp, pein);

  // 1. PE MLP: 64 -> 256 (relu) -> 128 (f16 posE)
  gemm_h<true, 1><<<2 * 625, 256, 0, stream>>>(pein, wPE1, pe_b1, nullptr, hpe, PN, 256, 64, 2);
  gemm_h<false, 1><<<1 * 625, 256, 0, stream>>>(hpe, wPE2, pe_b2, nullptr, posE, PN, 128, 256, 1);

  // 2. level-weight softmax
  lw_kernel<<<PN / 16, 256, 0, stream>>>(posE, wt_w, wt_b, lwga);

  // 3. fused projection + sampling -> X0 f16
  sample_kernel<<<PN / 8, 256, 0, stream>>>(f16b, rp, l2i, lwga, posE, X0);

  // 4. head MLP: 512 -> 1024 -> 1024 -> 1024 -> 128
  gemm_h<true, 1><<<8 * 157, 256, 0, stream>>>(X0, wH1, hm_b1, nullptr, H1, QN, 1024, 512, 8);
  gemm_h<true, 1><<<8 * 157, 256, 0, stream>>>(H1, wH2, hm_b2, nullptr, H2, QN, 1024, 1024, 8);
  gemm_h<true, 1><<<8 * 157, 256, 0, stream>>>(H2, wH3, hm_b3, nullptr, H3, QN, 1024, 1024, 8);
  gemm_h<false, 0><<<1 * 157, 256, 0, stream>>>(H3, wH4, hm_b4, out, nullptr, QN, 128, 1024, 1);
}